// Round 6
// baseline (369.029 us; speedup 1.0000x reference)
//
#include <hip/hip_runtime.h>
#include <hip/hip_bf16.h>
#include <stdint.h>

#define DIM 256
#define TOPK 8
#define NSTRIPS 128                  // 128 strips x 782 rows; grid 8x128=1024 = 4 blocks/CU
#define STRIP_TOP 8                  // per (query,strip) top-8
#define QT 256                       // 8-wave 512-thread blocks, 32 queries/wave
#define NT 32                        // 32-row tiles: acc[2][2] = 16 regs
#define CAND (NSTRIPS * STRIP_TOP)   // 1024 = 4 waves x 256 keys exactly
#define RESCORE 64
#define IDXMASK 0x1FFFFu

typedef __attribute__((ext_vector_type(8))) short short8;
typedef __attribute__((ext_vector_type(4))) float floatx4;
typedef __attribute__((address_space(3))) unsigned int lds_u32;
typedef __attribute__((address_space(1))) const unsigned int gbl_u32;

__device__ __forceinline__ unsigned short f2bf(float f) {
    union { float f; uint32_t u; } v; v.f = f;
    uint32_t u = v.u;
    uint32_t r = u + 0x7fffu + ((u >> 16) & 1u);   // RNE
    return (unsigned short)(r >> 16);
}

__device__ __forceinline__ uint32_t umaxu(uint32_t a, uint32_t b) { return a > b ? a : b; }
__device__ __forceinline__ uint32_t uminu(uint32_t a, uint32_t b) { return a < b ? a : b; }

// sorted-ascending top-8 insert: new[j] = med3(old[j], old[j+1], key); new[7]=max
__device__ __forceinline__ void top8_insert(uint32_t* ts, uint32_t key) {
#pragma unroll
    for (int j = 0; j < STRIP_TOP - 1; j++) {
        uint32_t m;
        asm("v_med3_u32 %0, %1, %2, %3" : "=v"(m) : "v"(ts[j]), "v"(ts[j + 1]), "v"(key));
        ts[j] = m;
    }
    ts[STRIP_TOP - 1] = umaxu(ts[STRIP_TOP - 1], key);
}

// ---------------- Kernel 1: norms + normalized bf16 copies ----------------
__global__ void prep_kernel(const float* __restrict__ query,
                            const float* __restrict__ mem,
                            float* __restrict__ rnorm_mem,
                            unsigned short* __restrict__ q_bf16,
                            unsigned short* __restrict__ mem_bf16,  // may be null
                            int B, int N)
{
    int wave = threadIdx.x >> 6;
    int lane = threadIdx.x & 63;
    int row  = blockIdx.x * 4 + wave;
    int total = N + B;
    if (row >= total) return;
    const float* src = (row < N) ? (mem + (size_t)row * DIM)
                                 : (query + (size_t)(row - N) * DIM);
    float4 v = ((const float4*)src)[lane];
    float ss = v.x * v.x + v.y * v.y + v.z * v.z + v.w * v.w;
#pragma unroll
    for (int m = 32; m >= 1; m >>= 1) ss += __shfl_xor(ss, m, 64);
    float rinv = 1.0f / fmaxf(sqrtf(ss), 1e-12f);
    ushort4 o;
    o.x = f2bf(v.x * rinv); o.y = f2bf(v.y * rinv);
    o.z = f2bf(v.z * rinv); o.w = f2bf(v.w * rinv);
    if (row < N) {
        if (lane == 0) rnorm_mem[row] = rinv;
        if (mem_bf16) ((ushort4*)(mem_bf16 + (size_t)row * DIM))[lane] = o;
    } else {
        ((ushort4*)(q_bf16 + (size_t)(row - N) * DIM))[lane] = o;
    }
}

// ---------------- Kernel 2: swapped-operand MFMA scoring, in-register top-8 ----------------
// D = mfma(A=mem rows, B=query cols): col(lane&15)=query, row(quad*4+r)=mem row.
// Selection: pure-register med3 ripple with pair-max always / pair-min gated by __any.
// Quad-substream top-8s merged via shfl_xor (no LDS scratch) -> LDS = 32 KB total.
// Grid 1024 blocks = 4 blocks/CU (8 waves each) -> up to 32 waves/CU resident.
// Bias 1.125 keeps biased scores strictly positive so raw fp32 bits are monotone.
template<bool PRE>
__global__ __launch_bounds__(512, 4) void score_select_kernel(
    const float* __restrict__ mem,
    const float* __restrict__ rnorm_mem,
    const unsigned short* __restrict__ mem_bf16,
    const unsigned short* __restrict__ q_bf16,
    uint32_t* __restrict__ cand_key,
    int B, int N)
{
    __shared__ unsigned short lds_m[2][NT * DIM];   // 2 x 16384 B, XOR-swizzled rows

    const int t    = threadIdx.x;
    const int wave = t >> 6;                       // 0..7
    const int lane = t & 63;
    const int quad = lane >> 4;
    const int l16  = lane & 15;

    // XCD-bijective swizzle: all 8 qb-peers of a strip share lin&7 (same XCD).
    const int lin  = (int)(blockIdx.x + gridDim.x * blockIdx.y);
    const int SPX  = NSTRIPS / 8;                  // strips per XCD = 16
    const int strip = (lin & 7) * SPX + ((lin >> 3) % SPX);
    const int qb    = (lin >> 3) / SPX;
    const int qbase = qb * QT;

    const int SS    = (N + NSTRIPS - 1) / NSTRIPS; // 782
    const int n0    = strip * SS;
    const int nend  = (n0 + SS < N) ? (n0 + SS) : N;
    const int limit = nend - n0;                    // valid strip-local rows
    const int ntiles = (limit + NT - 1) / NT;

    // Query fragments (B operand): wave owns 32 queries qbase + wave*32 + b*16 + l16.
    short8 qfrag[2][8];
#pragma unroll
    for (int b = 0; b < 2; b++) {
        int qrow = qbase + wave * 32 + b * 16 + l16;
        const unsigned short* qp = q_bf16 + (size_t)qrow * DIM + quad * 8;
#pragma unroll
        for (int ks = 0; ks < 8; ks++)
            qfrag[b][ks] = *(const short8*)(qp + ks * 32);
    }

    // per-lane top-8 keys (ascending) for each of its 2 queries
    uint32_t ts[2][STRIP_TOP];
#pragma unroll
    for (int b = 0; b < 2; b++)
#pragma unroll
        for (int j = 0; j < STRIP_TOP; j++) ts[b][j] = 0;

    const int l5  = lane >> 5;   // 0/1
    const int s32 = lane & 31;

    auto stage = [&](unsigned short* lbase, int tileIdx) {
        int base = n0 + tileIdx * NT;
        if (PRE) {
#pragma unroll
            for (int is = 0; is < 2; is++) {
                int rl = is * 16 + wave * 2 + l5;
                int n = base + rl; if (n >= nend) n = nend - 1;
                int chunk = s32 ^ (rl & 7);
                const unsigned short* gp = mem_bf16 + (size_t)n * DIM + chunk * 8;
                unsigned short* lp = lbase + (is * 16 + wave * 2) * DIM;  // wave-uniform
                __builtin_amdgcn_global_load_lds((gbl_u32*)(const void*)gp,
                                                 (lds_u32*)(void*)lp, 16, 0, 0);
            }
        } else {
#pragma unroll
            for (int i = 0; i < 4; i++) {
                int rl = i * 8 + wave;
                int n = base + rl;
                ushort4 o;
                if (n < nend) {
                    float rinv = rnorm_mem[n];
                    float4 v = ((const float4*)(mem + (size_t)n * DIM))[lane];
                    o.x = f2bf(v.x * rinv); o.y = f2bf(v.y * rinv);
                    o.z = f2bf(v.z * rinv); o.w = f2bf(v.w * rinv);
                } else { o.x = 0; o.y = 0; o.z = 0; o.w = 0; }
                int slot = (lane >> 1) ^ (rl & 7);
                *(ushort4*)(lbase + rl * DIM + slot * 8 + (lane & 1) * 4) = o;
            }
        }
    };

    stage(&lds_m[0][0], 0);
    __syncthreads();

    const floatx4 bias4 = {1.125f, 1.125f, 1.125f, 1.125f};  // strictly positive biased scores
    for (int tile = 0; tile < ntiles; tile++) {
        unsigned short* lbuf = &lds_m[tile & 1][0];
        if (tile + 1 < ntiles) stage(&lds_m[(tile + 1) & 1][0], tile + 1);  // in flight over MFMA

        floatx4 acc[2][2];
#pragma unroll
        for (int a = 0; a < 2; a++)
#pragma unroll
            for (int b = 0; b < 2; b++) acc[a][b] = bias4;

#pragma unroll
        for (int ks = 0; ks < 8; ks++) {
#pragma unroll
            for (int a = 0; a < 2; a++) {
                int row = a * 16 + l16;
                int slot = (ks * 4 + quad) ^ (l16 & 7);
                short8 m = *(const short8*)(lbuf + row * DIM + slot * 8);
#pragma unroll
                for (int b = 0; b < 2; b++)
                    acc[a][b] = __builtin_amdgcn_mfma_f32_16x16x32_bf16(m, qfrag[b][ks], acc[a][b], 0, 0, 0);
            }
        }

        // selection: pair-max always rippled, pair-min gated (exact).
        // loc = tile*32 + a*16 + quad*4 + r.
        const int tb0 = tile * NT + quad * 4;
        const bool full = (tile * NT + NT <= limit);
#pragma unroll
        for (int b = 0; b < 2; b++) {
#pragma unroll
            for (int a = 0; a < 2; a++) {
#pragma unroll
                for (int rp = 0; rp < 2; rp++) {
                    int loc0 = tb0 + a * 16 + 2 * rp;
                    uint32_t k0 = (__float_as_uint(acc[a][b][2 * rp])     & 0xFFFF0000u) | (uint32_t)loc0;
                    uint32_t k1 = (__float_as_uint(acc[a][b][2 * rp + 1]) & 0xFFFF0000u) | (uint32_t)(loc0 + 1);
                    if (!full) {
                        if (loc0 >= limit)     k0 = 0;
                        if (loc0 + 1 >= limit) k1 = 0;
                    }
                    uint32_t kmax = umaxu(k0, k1);
                    uint32_t kmin = uminu(k0, k1);
                    top8_insert(ts[b], kmax);
                    if (__any(kmin > ts[b][0]))
                        top8_insert(ts[b], kmin);   // no-op for non-qualifying lanes
                }
            }
        }

        __syncthreads();   // everyone done reading lbuf; stage-writes to other buf drained
    }

    // ---- exact merge of the 4 quad-substreams per query via shfl (no LDS) ----
    // substreams for query (wave,b,l16) live in lanes {l16, l16+16, l16+32, l16+48}
#pragma unroll
    for (int b = 0; b < 2; b++) {
#pragma unroll
        for (int step = 32; step >= 16; step >>= 1) {
            uint32_t other[STRIP_TOP];
#pragma unroll
            for (int j = 0; j < STRIP_TOP; j++)
                other[j] = __shfl_xor(ts[b][j], step, 64);
#pragma unroll
            for (int j = 0; j < STRIP_TOP; j++)
                top8_insert(ts[b], other[j]);
        }
    }

    // write candidates from quad-0 lanes, converting to (score15 << 17 | gidx17)
    if (quad == 0) {
#pragma unroll
        for (int b = 0; b < 2; b++) {
            int q = qbase + wave * 32 + b * 16 + l16;
            size_t off = ((size_t)q * NSTRIPS + strip) * STRIP_TOP;
            uint4 o0, o1;
            uint32_t k;
            k = ts[b][0]; o0.x = ((k >> 17) << 17) | (uint32_t)(n0 + (int)(k & 0xFFFFu));
            k = ts[b][1]; o0.y = ((k >> 17) << 17) | (uint32_t)(n0 + (int)(k & 0xFFFFu));
            k = ts[b][2]; o0.z = ((k >> 17) << 17) | (uint32_t)(n0 + (int)(k & 0xFFFFu));
            k = ts[b][3]; o0.w = ((k >> 17) << 17) | (uint32_t)(n0 + (int)(k & 0xFFFFu));
            k = ts[b][4]; o1.x = ((k >> 17) << 17) | (uint32_t)(n0 + (int)(k & 0xFFFFu));
            k = ts[b][5]; o1.y = ((k >> 17) << 17) | (uint32_t)(n0 + (int)(k & 0xFFFFu));
            k = ts[b][6]; o1.z = ((k >> 17) << 17) | (uint32_t)(n0 + (int)(k & 0xFFFFu));
            k = ts[b][7]; o1.w = ((k >> 17) << 17) | (uint32_t)(n0 + (int)(k & 0xFFFFu));
            ((uint4*)(cand_key + off))[0] = o0;
            ((uint4*)(cand_key + off))[1] = o1;
        }
    }
}

// ---------------- Kernel 3: key sort, top-64 cut, fp64 rescore, top-8, gather ----------------
__global__ __launch_bounds__(256) void rescore_kernel(
    const float* __restrict__ query,
    const float* __restrict__ mem,
    const uint32_t* __restrict__ cand_key,
    float* __restrict__ out,
    int B, int N)
{
    __shared__ uint32_t cs[CAND];
    __shared__ float  lds_q[DIM];
    __shared__ double red[4];
    __shared__ double qss_sh;
    __shared__ int    sel_i[RESCORE];
    __shared__ double rs[RESCORE];
    __shared__ double best_s[TOPK];
    __shared__ int    best_i[TOPK];

    const int t    = threadIdx.x;
    const int q    = blockIdx.x;
    const int lane = t & 63;
    const int wave = t >> 6;

    for (int i = t; i < CAND; i += 256)
        cs[i] = cand_key[(size_t)q * CAND + i];

    float qv = query[(size_t)q * DIM + t];
    lds_q[t] = qv;
    double p = (double)qv * (double)qv;
#pragma unroll
    for (int m = 32; m >= 1; m >>= 1) p += __shfl_xor(p, m, 64);
    if (lane == 0) red[wave] = p;
    __syncthreads();
    if (t == 0) qss_sh = red[0] + red[1] + red[2] + red[3];

    // per-wave bitonic sort (descending) of its 256-key quarter; wave-synchronous
    {
        uint32_t* qcs = cs + wave * 256;
        for (int k = 2; k <= 256; k <<= 1) {
            for (int j = k >> 1; j > 0; j >>= 1) {
#pragma unroll
                for (int rep = 0; rep < 2; rep++) {
                    int c  = lane + rep * 64;
                    int i  = 2 * c - (c & (j - 1));
                    int ip = i + j;
                    bool up = ((i & k) == 0);
                    uint32_t a = qcs[i], b2 = qcs[ip];
                    bool aFirst = a > b2;
                    bool doSwap = up ? (!aFirst) : aFirst;
                    if (doSwap) { qcs[i] = b2; qcs[ip] = a; }
                }
            }
        }
        if (lane < 16) sel_i[wave * 16 + lane] = (int)(qcs[lane] & IDXMASK);
    }
    __syncthreads();

    // fp64 exact cosine for the 64 selected; each wave handles its 16
    double qss = qss_sh;
    for (int r = 0; r < 16; r++) {
        int c = wave * 16 + r;
        int idx = sel_i[c];
        float4 mv = ((const float4*)(mem + (size_t)idx * DIM))[lane];
        float4 qv4 = ((const float4*)lds_q)[lane];
        double dqm = (double)mv.x * (double)qv4.x + (double)mv.y * (double)qv4.y
                   + (double)mv.z * (double)qv4.z + (double)mv.w * (double)qv4.w;
        double dmm = (double)mv.x * (double)mv.x + (double)mv.y * (double)mv.y
                   + (double)mv.z * (double)mv.z + (double)mv.w * (double)mv.w;
#pragma unroll
        for (int m = 32; m >= 1; m >>= 1) {
            dqm += __shfl_xor(dqm, m, 64);
            dmm += __shfl_xor(dmm, m, 64);
        }
        if (lane == 0)
            rs[c] = dqm / (fmax(sqrt(qss), 1e-12) * fmax(sqrt(dmm), 1e-12));
    }
    __syncthreads();

    if (t == 0) {   // serial exact top-8, tie-break (score desc, idx asc)
        double bs[TOPK]; int bi[TOPK];
        for (int i = 0; i < TOPK; i++) { bs[i] = -1e300; bi[i] = 0x7fffffff; }
        for (int c = 0; c < RESCORE; c++) {
            double s = rs[c]; int id = sel_i[c];
            bool better = (s > bs[TOPK - 1]) || (s == bs[TOPK - 1] && id < bi[TOPK - 1]);
            if (better) {
                int pos = TOPK - 1;
                while (pos > 0) {
                    bool b2 = (s > bs[pos - 1]) || (s == bs[pos - 1] && id < bi[pos - 1]);
                    if (!b2) break;
                    bs[pos] = bs[pos - 1]; bi[pos] = bi[pos - 1]; pos--;
                }
                bs[pos] = s; bi[pos] = id;
            }
        }
        for (int i = 0; i < TOPK; i++) { best_s[i] = bs[i]; best_i[i] = bi[i]; }
    }
    __syncthreads();

    size_t score_base = (size_t)B * TOPK * DIM;
    if (t < TOPK) out[score_base + (size_t)q * TOPK + t] = (float)best_s[t];

#pragma unroll
    for (int rep = 0; rep < 2; rep++) {
        int j  = t >> 5;
        int d4 = (t & 31) + rep * 32;
        int idx = best_i[j];
        float4 v = ((const float4*)(mem + (size_t)idx * DIM))[d4];
        ((float4*)(out + ((size_t)q * TOPK + j) * DIM))[d4] = v;
    }
}

extern "C" void kernel_launch(void* const* d_in, const int* in_sizes, int n_in,
                              void* d_out, int out_size, void* d_ws, size_t ws_size,
                              hipStream_t stream)
{
    const float* query = (const float*)d_in[0];
    const float* mem   = (const float*)d_in[1];
    int B = in_sizes[0] / DIM;
    int N = in_sizes[1] / DIM;

    auto align256 = [](size_t x) { return (x + 255) & ~(size_t)255; };
    size_t off = 0;
    auto alloc = [&](size_t bytes) { void* p = (char*)d_ws + off; off += align256(bytes); return p; };

    float* rnorm_mem       = (float*)alloc((size_t)N * 4);
    unsigned short* q_bf16 = (unsigned short*)alloc((size_t)B * DIM * 2);
    uint32_t* cand_key     = (uint32_t*)alloc((size_t)B * CAND * 4);
    size_t base_need = off;
    unsigned short* mem_bf16 = (unsigned short*)((char*)d_ws + base_need);
    bool pre = (base_need + align256((size_t)N * DIM * 2)) <= ws_size;
    if (!pre) mem_bf16 = nullptr;

    int prep_blocks = (N + B + 3) / 4;
    prep_kernel<<<prep_blocks, 256, 0, stream>>>(query, mem, rnorm_mem, q_bf16,
                                                 mem_bf16, B, N);

    dim3 g2((B + QT - 1) / QT, NSTRIPS);
    if (pre)
        score_select_kernel<true><<<g2, 512, 0, stream>>>(mem, rnorm_mem, mem_bf16, q_bf16,
                                                          cand_key, B, N);
    else
        score_select_kernel<false><<<g2, 512, 0, stream>>>(mem, rnorm_mem, mem_bf16, q_bf16,
                                                           cand_key, B, N);

    rescore_kernel<<<B, 256, 0, stream>>>(query, mem, cand_key, (float*)d_out, B, N);
}

// Round 7
// 345.565 us; speedup vs baseline: 1.0679x; 1.0679x over previous
//
#include <hip/hip_runtime.h>
#include <hip/hip_bf16.h>
#include <stdint.h>

#define DIM 256
#define TOPK 8
#define NSTRIPS 64
#define STRIP_TOP 8                  // per (query,strip) top-8
#define QT 256                       // 8-wave 512-thread blocks, 32 queries/wave
#define NT 32                        // 32-row tiles: acc[2][2] = 16 regs
#define CAND (NSTRIPS * STRIP_TOP)   // 512
#define RESCORE 64
#define IDXMASK 0x1FFFFu

typedef __attribute__((ext_vector_type(8))) short short8;
typedef __attribute__((ext_vector_type(4))) float floatx4;
typedef __attribute__((address_space(3))) unsigned int lds_u32;
typedef __attribute__((address_space(1))) const unsigned int gbl_u32;

__device__ __forceinline__ unsigned short f2bf(float f) {
    union { float f; uint32_t u; } v; v.f = f;
    uint32_t u = v.u;
    uint32_t r = u + 0x7fffu + ((u >> 16) & 1u);   // RNE
    return (unsigned short)(r >> 16);
}

__device__ __forceinline__ uint32_t umaxu(uint32_t a, uint32_t b) { return a > b ? a : b; }
__device__ __forceinline__ uint32_t uminu(uint32_t a, uint32_t b) { return a < b ? a : b; }

// sorted-ascending top-8 insert: new[j] = med3(old[j], old[j+1], key); new[7]=max
__device__ __forceinline__ void top8_insert(uint32_t* ts, uint32_t key) {
#pragma unroll
    for (int j = 0; j < STRIP_TOP - 1; j++) {
        uint32_t m;
        asm("v_med3_u32 %0, %1, %2, %3" : "=v"(m) : "v"(ts[j]), "v"(ts[j + 1]), "v"(key));
        ts[j] = m;
    }
    ts[STRIP_TOP - 1] = umaxu(ts[STRIP_TOP - 1], key);
}

// ---------------- Kernel 1: norms + normalized bf16 copies ----------------
__global__ void prep_kernel(const float* __restrict__ query,
                            const float* __restrict__ mem,
                            float* __restrict__ rnorm_mem,
                            unsigned short* __restrict__ q_bf16,
                            unsigned short* __restrict__ mem_bf16,  // may be null
                            int B, int N)
{
    int wave = threadIdx.x >> 6;
    int lane = threadIdx.x & 63;
    int row  = blockIdx.x * 4 + wave;
    int total = N + B;
    if (row >= total) return;
    const float* src = (row < N) ? (mem + (size_t)row * DIM)
                                 : (query + (size_t)(row - N) * DIM);
    float4 v = ((const float4*)src)[lane];
    float ss = v.x * v.x + v.y * v.y + v.z * v.z + v.w * v.w;
#pragma unroll
    for (int m = 32; m >= 1; m >>= 1) ss += __shfl_xor(ss, m, 64);
    float rinv = 1.0f / fmaxf(sqrtf(ss), 1e-12f);
    ushort4 o;
    o.x = f2bf(v.x * rinv); o.y = f2bf(v.y * rinv);
    o.z = f2bf(v.z * rinv); o.w = f2bf(v.w * rinv);
    if (row < N) {
        if (lane == 0) rnorm_mem[row] = rinv;
        if (mem_bf16) ((ushort4*)(mem_bf16 + (size_t)row * DIM))[lane] = o;
    } else {
        ((ushort4*)(q_bf16 + (size_t)(row - N) * DIM))[lane] = o;
    }
}

// ---------------- Kernel 2: swapped-operand MFMA scoring, in-register top-8 ----------------
// D = mfma(A=mem rows, B=query cols): col(lane&15)=query, row(quad*4+r)=mem row.
// Selection: pure-register med3 ripple with pair-max always / pair-min gated by __any.
// Quad-substream top-8s merged via shfl_xor (no LDS scratch).
// 4-deep LDS ring (64 KB), TWO tiles computed per barrier: stages for t+2,t+3 issued
// before computing t,t+1 -> load latency window ~2x compute, barrier count halved.
// ds_read swizzle folded into two per-lane base pointers + compile-time immediates:
//   slot=(ks*4+quad)^(l16&7): bits0-1 lane-const, bit2 = (ks&1)^l16b2 (o1=o0^64),
//   bits3-4 = ks>>1 (immediate). All 16 ds_read_b128 are base+imm.
// Bias 1.125 keeps biased scores strictly positive so raw fp32 bits are monotone.
template<bool PRE>
__global__ __launch_bounds__(512, 4) void score_select_kernel(
    const float* __restrict__ mem,
    const float* __restrict__ rnorm_mem,
    const unsigned short* __restrict__ mem_bf16,
    const unsigned short* __restrict__ q_bf16,
    uint32_t* __restrict__ cand_key,
    int B, int N)
{
    __shared__ unsigned short lds_m[4][NT * DIM];   // 4 x 16384 B ring, XOR-swizzled rows

    const int t    = threadIdx.x;
    const int wave = t >> 6;                       // 0..7
    const int lane = t & 63;
    const int quad = lane >> 4;
    const int l16  = lane & 15;

    // XCD-bijective swizzle: all 8 qb-peers of a strip share lin&7 (same XCD).
    const int lin  = (int)(blockIdx.x + gridDim.x * blockIdx.y);
    const int SPX  = NSTRIPS / 8;                  // strips per XCD = 8
    const int strip = (lin & 7) * SPX + ((lin >> 3) % SPX);
    const int qb    = (lin >> 3) / SPX;
    const int qbase = qb * QT;

    const int SS    = (N + NSTRIPS - 1) / NSTRIPS; // 1563
    const int n0    = strip * SS;
    const int nend  = (n0 + SS < N) ? (n0 + SS) : N;
    const int limit = nend - n0;                    // valid strip-local rows
    const int ntiles = (limit + NT - 1) / NT;

    // Query fragments (B operand): wave owns 32 queries qbase + wave*32 + b*16 + l16.
    short8 qfrag[2][8];
#pragma unroll
    for (int b = 0; b < 2; b++) {
        int qrow = qbase + wave * 32 + b * 16 + l16;
        const unsigned short* qp = q_bf16 + (size_t)qrow * DIM + quad * 8;
#pragma unroll
        for (int ks = 0; ks < 8; ks++)
            qfrag[b][ks] = *(const short8*)(qp + ks * 32);
    }

    // per-lane top-8 keys (ascending) for each of its 2 queries
    uint32_t ts[2][STRIP_TOP];
#pragma unroll
    for (int b = 0; b < 2; b++)
#pragma unroll
        for (int j = 0; j < STRIP_TOP; j++) ts[b][j] = 0;

    const int l5  = lane >> 5;   // 0/1
    const int s32 = lane & 31;

    // dual ds_read base offsets (bytes): lane-dependent part of the swizzled address
    const int o0 = l16 * 512 + (quad ^ (l16 & 3)) * 16 + ((l16 >> 2) & 1) * 64;
    const int o1 = o0 ^ 64;

    auto stage = [&](unsigned short* lbase, int tileIdx) {
        int base = n0 + tileIdx * NT;
        if (PRE) {
#pragma unroll
            for (int is = 0; is < 2; is++) {
                int rl = is * 16 + wave * 2 + l5;
                int n = base + rl; if (n >= nend) n = nend - 1;
                int chunk = s32 ^ (rl & 7);
                const unsigned short* gp = mem_bf16 + (size_t)n * DIM + chunk * 8;
                unsigned short* lp = lbase + (is * 16 + wave * 2) * DIM;  // wave-uniform
                __builtin_amdgcn_global_load_lds((gbl_u32*)(const void*)gp,
                                                 (lds_u32*)(void*)lp, 16, 0, 0);
            }
        } else {
#pragma unroll
            for (int i = 0; i < 4; i++) {
                int rl = i * 8 + wave;
                int n = base + rl;
                ushort4 o;
                if (n < nend) {
                    float rinv = rnorm_mem[n];
                    float4 v = ((const float4*)(mem + (size_t)n * DIM))[lane];
                    o.x = f2bf(v.x * rinv); o.y = f2bf(v.y * rinv);
                    o.z = f2bf(v.z * rinv); o.w = f2bf(v.w * rinv);
                } else { o.x = 0; o.y = 0; o.z = 0; o.w = 0; }
                int slot = (lane >> 1) ^ (rl & 7);
                *(ushort4*)(lbase + rl * DIM + slot * 8 + (lane & 1) * 4) = o;
            }
        }
    };

    const floatx4 bias4 = {1.125f, 1.125f, 1.125f, 1.125f};  // strictly positive biased scores

    auto compute_tile = [&](const unsigned short* lbuf, int tile) {
        floatx4 acc[2][2];
#pragma unroll
        for (int a = 0; a < 2; a++)
#pragma unroll
            for (int b = 0; b < 2; b++) acc[a][b] = bias4;

        const char* pb0 = (const char*)lbuf + o0;
        const char* pb1 = (const char*)lbuf + o1;
#pragma unroll
        for (int ks = 0; ks < 8; ks++) {
#pragma unroll
            for (int a = 0; a < 2; a++) {
                const char* p = (ks & 1) ? pb1 : pb0;
                short8 m = *(const short8*)(p + a * 8192 + (ks >> 1) * 128);
#pragma unroll
                for (int b = 0; b < 2; b++)
                    acc[a][b] = __builtin_amdgcn_mfma_f32_16x16x32_bf16(m, qfrag[b][ks], acc[a][b], 0, 0, 0);
            }
        }

        // selection: pair-max always rippled, pair-min gated (exact).
        // loc = tile*32 + a*16 + quad*4 + r.
        const int tb0 = tile * NT + quad * 4;
        const bool full = (tile * NT + NT <= limit);
#pragma unroll
        for (int b = 0; b < 2; b++) {
#pragma unroll
            for (int a = 0; a < 2; a++) {
#pragma unroll
                for (int rp = 0; rp < 2; rp++) {
                    int loc0 = tb0 + a * 16 + 2 * rp;
                    uint32_t k0 = (__float_as_uint(acc[a][b][2 * rp])     & 0xFFFF0000u) | (uint32_t)loc0;
                    uint32_t k1 = (__float_as_uint(acc[a][b][2 * rp + 1]) & 0xFFFF0000u) | (uint32_t)(loc0 + 1);
                    if (!full) {
                        if (loc0 >= limit)     k0 = 0;
                        if (loc0 + 1 >= limit) k1 = 0;
                    }
                    uint32_t kmax = umaxu(k0, k1);
                    uint32_t kmin = uminu(k0, k1);
                    top8_insert(ts[b], kmax);
                    if (__any(kmin > ts[b][0]))
                        top8_insert(ts[b], kmin);   // no-op for non-qualifying lanes
                }
            }
        }
    };

    stage(&lds_m[0][0], 0);
    if (1 < ntiles) stage(&lds_m[1][0], 1);
    __syncthreads();

    for (int tp = 0; tp < ntiles; tp += 2) {
        if (tp + 2 < ntiles) stage(&lds_m[(tp + 2) & 3][0], tp + 2);
        if (tp + 3 < ntiles) stage(&lds_m[(tp + 3) & 3][0], tp + 3);
        compute_tile(&lds_m[tp & 3][0], tp);
        if (tp + 1 < ntiles) compute_tile(&lds_m[(tp + 1) & 3][0], tp + 1);
        __syncthreads();   // readers done with tp,tp+1; staged loads for tp+2,tp+3 drained
    }

    // ---- exact merge of the 4 quad-substreams per query via shfl (no LDS) ----
    // substreams for query (wave,b,l16) live in lanes {l16, l16+16, l16+32, l16+48}
#pragma unroll
    for (int b = 0; b < 2; b++) {
#pragma unroll
        for (int step = 32; step >= 16; step >>= 1) {
            uint32_t other[STRIP_TOP];
#pragma unroll
            for (int j = 0; j < STRIP_TOP; j++)
                other[j] = __shfl_xor(ts[b][j], step, 64);
#pragma unroll
            for (int j = 0; j < STRIP_TOP; j++)
                top8_insert(ts[b], other[j]);
        }
    }

    // write candidates from quad-0 lanes, converting to (score15 << 17 | gidx17)
    if (quad == 0) {
#pragma unroll
        for (int b = 0; b < 2; b++) {
            int q = qbase + wave * 32 + b * 16 + l16;
            size_t off = ((size_t)q * NSTRIPS + strip) * STRIP_TOP;
            uint4 o0v, o1v;
            uint32_t k;
            k = ts[b][0]; o0v.x = ((k >> 17) << 17) | (uint32_t)(n0 + (int)(k & 0xFFFFu));
            k = ts[b][1]; o0v.y = ((k >> 17) << 17) | (uint32_t)(n0 + (int)(k & 0xFFFFu));
            k = ts[b][2]; o0v.z = ((k >> 17) << 17) | (uint32_t)(n0 + (int)(k & 0xFFFFu));
            k = ts[b][3]; o0v.w = ((k >> 17) << 17) | (uint32_t)(n0 + (int)(k & 0xFFFFu));
            k = ts[b][4]; o1v.x = ((k >> 17) << 17) | (uint32_t)(n0 + (int)(k & 0xFFFFu));
            k = ts[b][5]; o1v.y = ((k >> 17) << 17) | (uint32_t)(n0 + (int)(k & 0xFFFFu));
            k = ts[b][6]; o1v.z = ((k >> 17) << 17) | (uint32_t)(n0 + (int)(k & 0xFFFFu));
            k = ts[b][7]; o1v.w = ((k >> 17) << 17) | (uint32_t)(n0 + (int)(k & 0xFFFFu));
            ((uint4*)(cand_key + off))[0] = o0v;
            ((uint4*)(cand_key + off))[1] = o1v;
        }
    }
}

// ---------------- Kernel 3: key sort, top-64 cut, fp64 rescore, top-8, gather ----------------
__global__ __launch_bounds__(256) void rescore_kernel(
    const float* __restrict__ query,
    const float* __restrict__ mem,
    const uint32_t* __restrict__ cand_key,
    float* __restrict__ out,
    int B, int N)
{
    __shared__ uint32_t cs[CAND];
    __shared__ float  lds_q[DIM];
    __shared__ double red[4];
    __shared__ double qss_sh;
    __shared__ int    sel_i[RESCORE];
    __shared__ double rs[RESCORE];
    __shared__ double best_s[TOPK];
    __shared__ int    best_i[TOPK];

    const int t    = threadIdx.x;
    const int q    = blockIdx.x;
    const int lane = t & 63;
    const int wave = t >> 6;

    for (int i = t; i < CAND; i += 256)
        cs[i] = cand_key[(size_t)q * CAND + i];

    float qv = query[(size_t)q * DIM + t];
    lds_q[t] = qv;
    double p = (double)qv * (double)qv;
#pragma unroll
    for (int m = 32; m >= 1; m >>= 1) p += __shfl_xor(p, m, 64);
    if (lane == 0) red[wave] = p;
    __syncthreads();
    if (t == 0) qss_sh = red[0] + red[1] + red[2] + red[3];

    // per-wave bitonic sort (descending) of its 128-key quarter; wave-synchronous
    {
        uint32_t* qcs = cs + wave * 128;
        for (int k = 2; k <= 128; k <<= 1) {
            for (int j = k >> 1; j > 0; j >>= 1) {
                int i  = 2 * lane - (lane & (j - 1));
                int ip = i + j;
                bool up = ((i & k) == 0);
                uint32_t a = qcs[i], b2 = qcs[ip];
                bool aFirst = a > b2;
                bool doSwap = up ? (!aFirst) : aFirst;
                if (doSwap) { qcs[i] = b2; qcs[ip] = a; }
            }
        }
        if (lane < 16) sel_i[wave * 16 + lane] = (int)(qcs[lane] & IDXMASK);
    }
    __syncthreads();

    // fp64 exact cosine for the 64 selected; each wave handles its 16
    double qss = qss_sh;
    for (int r = 0; r < 16; r++) {
        int c = wave * 16 + r;
        int idx = sel_i[c];
        float4 mv = ((const float4*)(mem + (size_t)idx * DIM))[lane];
        float4 qv4 = ((const float4*)lds_q)[lane];
        double dqm = (double)mv.x * (double)qv4.x + (double)mv.y * (double)qv4.y
                   + (double)mv.z * (double)qv4.z + (double)mv.w * (double)qv4.w;
        double dmm = (double)mv.x * (double)mv.x + (double)mv.y * (double)mv.y
                   + (double)mv.z * (double)mv.z + (double)mv.w * (double)mv.w;
#pragma unroll
        for (int m = 32; m >= 1; m >>= 1) {
            dqm += __shfl_xor(dqm, m, 64);
            dmm += __shfl_xor(dmm, m, 64);
        }
        if (lane == 0)
            rs[c] = dqm / (fmax(sqrt(qss), 1e-12) * fmax(sqrt(dmm), 1e-12));
    }
    __syncthreads();

    if (t == 0) {   // serial exact top-8, tie-break (score desc, idx asc)
        double bs[TOPK]; int bi[TOPK];
        for (int i = 0; i < TOPK; i++) { bs[i] = -1e300; bi[i] = 0x7fffffff; }
        for (int c = 0; c < RESCORE; c++) {
            double s = rs[c]; int id = sel_i[c];
            bool better = (s > bs[TOPK - 1]) || (s == bs[TOPK - 1] && id < bi[TOPK - 1]);
            if (better) {
                int pos = TOPK - 1;
                while (pos > 0) {
                    bool b2 = (s > bs[pos - 1]) || (s == bs[pos - 1] && id < bi[pos - 1]);
                    if (!b2) break;
                    bs[pos] = bs[pos - 1]; bi[pos] = bi[pos - 1]; pos--;
                }
                bs[pos] = s; bi[pos] = id;
            }
        }
        for (int i = 0; i < TOPK; i++) { best_s[i] = bs[i]; best_i[i] = bi[i]; }
    }
    __syncthreads();

    size_t score_base = (size_t)B * TOPK * DIM;
    if (t < TOPK) out[score_base + (size_t)q * TOPK + t] = (float)best_s[t];

#pragma unroll
    for (int rep = 0; rep < 2; rep++) {
        int j  = t >> 5;
        int d4 = (t & 31) + rep * 32;
        int idx = best_i[j];
        float4 v = ((const float4*)(mem + (size_t)idx * DIM))[d4];
        ((float4*)(out + ((size_t)q * TOPK + j) * DIM))[d4] = v;
    }
}

extern "C" void kernel_launch(void* const* d_in, const int* in_sizes, int n_in,
                              void* d_out, int out_size, void* d_ws, size_t ws_size,
                              hipStream_t stream)
{
    const float* query = (const float*)d_in[0];
    const float* mem   = (const float*)d_in[1];
    int B = in_sizes[0] / DIM;
    int N = in_sizes[1] / DIM;

    auto align256 = [](size_t x) { return (x + 255) & ~(size_t)255; };
    size_t off = 0;
    auto alloc = [&](size_t bytes) { void* p = (char*)d_ws + off; off += align256(bytes); return p; };

    float* rnorm_mem       = (float*)alloc((size_t)N * 4);
    unsigned short* q_bf16 = (unsigned short*)alloc((size_t)B * DIM * 2);
    uint32_t* cand_key     = (uint32_t*)alloc((size_t)B * CAND * 4);
    size_t base_need = off;
    unsigned short* mem_bf16 = (unsigned short*)((char*)d_ws + base_need);
    bool pre = (base_need + align256((size_t)N * DIM * 2)) <= ws_size;
    if (!pre) mem_bf16 = nullptr;

    int prep_blocks = (N + B + 3) / 4;
    prep_kernel<<<prep_blocks, 256, 0, stream>>>(query, mem, rnorm_mem, q_bf16,
                                                 mem_bf16, B, N);

    dim3 g2((B + QT - 1) / QT, NSTRIPS);
    if (pre)
        score_select_kernel<true><<<g2, 512, 0, stream>>>(mem, rnorm_mem, mem_bf16, q_bf16,
                                                          cand_key, B, N);
    else
        score_select_kernel<false><<<g2, 512, 0, stream>>>(mem, rnorm_mem, mem_bf16, q_bf16,
                                                           cand_key, B, N);

    rescore_kernel<<<B, 256, 0, stream>>>(query, mem, cand_key, (float*)d_out, B, N);
}